// Round 1
// baseline (2225.183 us; speedup 1.0000x reference)
//
#include <hip/hip_runtime.h>
#include <math.h>

#define BB 8
#define TT 48
#define DD 512
#define NNN 1024

// ---------------- init: Gp = 0.5*I per batch, Gt = 0 ----------------
__global__ __launch_bounds__(256) void k_init(float* __restrict__ Gp, float* __restrict__ Gt) {
    size_t i = (size_t)blockIdx.x * blockDim.x + threadIdx.x;
    size_t stride = (size_t)gridDim.x * blockDim.x;
    const size_t nvec = (size_t)BB * NNN * NNN / 4;  // float4 count
    float4 z4 = make_float4(0.f, 0.f, 0.f, 0.f);
    for (size_t e = i; e < nvec; e += stride) {
        reinterpret_cast<float4*>(Gt)[e] = z4;
        size_t base = e * 4;
        size_t nm = base & ((size_t)NNN * NNN - 1);
        int n = (int)(nm >> 10);
        int m0 = (int)(nm & (NNN - 1));
        float4 v = z4;
        if (n >= m0 && n < m0 + 4) {
            if (n == m0)     v.x = 0.5f;
            else if (n == m0 + 1) v.y = 0.5f;
            else if (n == m0 + 2) v.z = 0.5f;
            else                  v.w = 0.5f;
        }
        reinterpret_cast<float4*>(Gp)[e] = v;
    }
}

// ---------------- z = [x ; tgt_next] @ E  (768 x 512 @ 512 x 1024) ----------------
__global__ __launch_bounds__(256) void k_gemm_z(const float* __restrict__ xs, const float* __restrict__ tg,
                                                const float* __restrict__ E,
                                                float* __restrict__ z_x, float* __restrict__ z_t) {
    int rt = blockIdx.x;          // 0..47  (row tile of 16)
    int ct = blockIdx.y;          // 0..3   (col tile of 256)
    int tid = threadIdx.x;        // 256
    __shared__ float Xs[16][DD];
    int row0 = rt * 16;
    for (int i = tid; i < 16 * DD; i += 256) {
        int r = i >> 9, d = i & (DD - 1);
        int gr = row0 + r;
        float v;
        if (gr < BB * TT) {
            v = xs[(size_t)gr * DD + d];
        } else {
            int bt = gr - BB * TT;
            int b = bt / TT, t = bt % TT;
            v = (t < TT - 1) ? tg[((size_t)b * TT + t + 1) * DD + d] : 0.f;
        }
        Xs[r][d] = v;
    }
    __syncthreads();
    int col = ct * 256 + tid;
    float acc[16];
#pragma unroll
    for (int r = 0; r < 16; r++) acc[r] = 0.f;
    for (int d = 0; d < DD; d++) {
        float e = E[(size_t)d * NNN + col];
#pragma unroll
        for (int r = 0; r < 16; r++) acc[r] = fmaf(Xs[r][d], e, acc[r]);
    }
#pragma unroll
    for (int r = 0; r < 16; r++) {
        int gr = row0 + r;
        if (gr < BB * TT) z_x[(size_t)gr * NNN + col] = acc[r];
        else              z_t[(size_t)(gr - BB * TT) * NNN + col] = acc[r];
    }
}

// ---------------- LN + relu + compaction of nonzero rows ----------------
__global__ __launch_bounds__(256) void k_ln(const float* __restrict__ z_x, const float* __restrict__ z_t,
                                            float* __restrict__ xn, float* __restrict__ tn,
                                            int* __restrict__ listn, float* __restrict__ listw,
                                            int* __restrict__ cnt) {
    int bt = blockIdx.x;          // b*TT + t
    int t = bt % TT;
    int tid = threadIdx.x;        // 256
    __shared__ float vals[NNN];
    __shared__ float rs_[256], rq_[256];
    __shared__ unsigned long long cmask[16];
    __shared__ int ccnt[16];

    // ---- xn row ----
    const float* src = z_x + (size_t)bt * NNN;
    float v0 = src[tid], v1 = src[tid + 256], v2 = src[tid + 512], v3 = src[tid + 768];
    rs_[tid] = v0 + v1 + v2 + v3;
    rq_[tid] = v0 * v0 + v1 * v1 + v2 * v2 + v3 * v3;
    __syncthreads();
    for (int off = 128; off > 0; off >>= 1) {
        if (tid < off) { rs_[tid] += rs_[tid + off]; rq_[tid] += rq_[tid + off]; }
        __syncthreads();
    }
    float mu = rs_[0] * (1.f / NNN);
    float var = rq_[0] * (1.f / NNN) - mu * mu;
    float rstd = rsqrtf(var + 1e-5f);
    float o0 = fmaxf((v0 - mu) * rstd, 0.f);
    float o1 = fmaxf((v1 - mu) * rstd, 0.f);
    float o2 = fmaxf((v2 - mu) * rstd, 0.f);
    float o3 = fmaxf((v3 - mu) * rstd, 0.f);
    vals[tid] = o0; vals[tid + 256] = o1; vals[tid + 512] = o2; vals[tid + 768] = o3;
    float* xrow = xn + (size_t)bt * NNN;
    xrow[tid] = o0; xrow[tid + 256] = o1; xrow[tid + 512] = o2; xrow[tid + 768] = o3;
    __syncthreads();

    // deterministic compaction (ascending n)
    int w = tid >> 6, l = tid & 63;
    unsigned long long lmask = (1ull << l) - 1ull;
    for (int k = 0; k < 4; k++) {
        int c = (w << 2) + k;
        bool f = vals[(c << 6) + l] > 0.f;
        unsigned long long mk = __ballot(f);
        if (l == 0) { cmask[c] = mk; ccnt[c] = __popcll(mk); }
    }
    __syncthreads();
    for (int k = 0; k < 4; k++) {
        int c = (w << 2) + k;
        int nidx = (c << 6) + l;
        if (vals[nidx] > 0.f) {
            int base = 0;
            for (int c2 = 0; c2 < c; c2++) base += ccnt[c2];
            int pos = base + __popcll(cmask[c] & lmask);
            listn[(size_t)bt * NNN + pos] = nidx;
            listw[(size_t)bt * NNN + pos] = vals[nidx];
        }
    }
    if (tid == 0) {
        int tot = 0;
        for (int c = 0; c < 16; c++) tot += ccnt[c];
        cnt[bt] = tot;
    }

    // ---- tn row ----
    float* trow = tn + (size_t)bt * NNN;
    if (t < TT - 1) {
        const float* s2 = z_t + (size_t)bt * NNN;
        float u0 = s2[tid], u1 = s2[tid + 256], u2 = s2[tid + 512], u3 = s2[tid + 768];
        __syncthreads();
        rs_[tid] = u0 + u1 + u2 + u3;
        rq_[tid] = u0 * u0 + u1 * u1 + u2 * u2 + u3 * u3;
        __syncthreads();
        for (int off = 128; off > 0; off >>= 1) {
            if (tid < off) { rs_[tid] += rs_[tid + off]; rq_[tid] += rq_[tid + off]; }
            __syncthreads();
        }
        float mu2 = rs_[0] * (1.f / NNN);
        float var2 = rq_[0] * (1.f / NNN) - mu2 * mu2;
        float r2 = rsqrtf(var2 + 1e-5f);
        trow[tid]       = fmaxf((u0 - mu2) * r2, 0.f);
        trow[tid + 256] = fmaxf((u1 - mu2) * r2, 0.f);
        trow[tid + 512] = fmaxf((u2 - mu2) * r2, 0.f);
        trow[tid + 768] = fmaxf((u3 - mu2) * r2, 0.f);
    } else {
        trow[tid] = 0.f; trow[tid + 256] = 0.f; trow[tid + 512] = 0.f; trow[tid + 768] = 0.f;
    }
}

// ---------------- per-step: blocks [0,128) = y epilogue of step t-1;
//                  blocks [128,640) = fused G sweep (r partials + max update) of step t ----
__global__ __launch_bounds__(256) void k_step(const float* __restrict__ Dy, const float* __restrict__ mixp,
                                              float* __restrict__ Gp, float* __restrict__ Gt,
                                              const float* __restrict__ xn, const float* __restrict__ tn,
                                              const int* __restrict__ listn, const float* __restrict__ listw,
                                              const int* __restrict__ cnt,
                                              float* __restrict__ r_part, float* __restrict__ out,
                                              int t, int do_upd) {
    int bx = blockIdx.x;
    int tid = threadIdx.x;
    if (bx < 128) {
        if (t == 0) return;                      // no y yet at first step
        __shared__ float mix[NNN];
        __shared__ float red[256];
        int b = bx >> 4, dt = bx & 15;
        int ty = t - 1;
        float alpha = 1.f / (1.f + expf(-mixp[0]));
        const float* rp = r_part + (size_t)(ty & 1) * (2 * 8 * 16 * 1024);
        for (int m = tid; m < NNN; m += 256) {
            float sp = 0.f, st = 0.f;
#pragma unroll
            for (int rc = 0; rc < 16; rc++) {
                sp += rp[(size_t)((0 * 8 + b) * 16 + rc) * NNN + m];
                st += rp[(size_t)((1 * 8 + b) * 16 + rc) * NNN + m];
            }
            mix[m] = alpha * sp + (1.f - alpha) * st;
        }
        __syncthreads();
        int mg = tid >> 5, dl = tid & 31;
        int d = dt * 32 + dl;
        float acc = 0.f;
        for (int m = mg; m < NNN; m += 8)
            acc = fmaf(mix[m], Dy[(size_t)m * DD + d], acc);
        red[tid] = acc;
        __syncthreads();
        for (int off = 4; off > 0; off >>= 1) {
            if (mg < off) red[tid] += red[tid + off * 32];
            __syncthreads();
        }
        if (mg == 0)
            out[((size_t)b * TT + ty) * DD + d] = fmaxf(red[tid], 0.f);
    } else {
        int gx = bx - 128;                       // [0,512)
        int state = gx & 1;
        int b = (gx >> 1) & 7;
        int ct = (gx >> 4) & 1;
        int rc = (gx >> 5) & 15;
        int bt = b * TT + t;
        int cb = cnt[bt];
        __shared__ int ln_s[NNN];
        __shared__ float lw_s[NNN];
        for (int s = tid; s < cb; s += 256) {
            ln_s[s] = listn[(size_t)bt * NNN + s];
            lw_s[s] = listw[(size_t)bt * NNN + s];
        }
        __syncthreads();
        int tr = tid >> 7, c = tid & 127;
        int m4 = ct * 128 + c;                   // float4 column index
        const float* vvec = (state ? tn : xn) + (size_t)bt * NNN;
        float4 vm = *reinterpret_cast<const float4*>(vvec + m4 * 4);
        float4 vh = make_float4(0.5f * vm.x, 0.5f * vm.y, 0.5f * vm.z, 0.5f * vm.w);
        float* G = (state ? Gt : Gp) + (size_t)b * NNN * NNN;
        float4 acc = make_float4(0.f, 0.f, 0.f, 0.f);
        for (int s = rc * 2 + tr; s < cb; s += 32) {
            int n = ln_s[s];
            float wn = lw_s[s];
            float4* gp = reinterpret_cast<float4*>(G + ((size_t)n << 10)) + m4;
            float4 g = *gp;
            acc.x = fmaf(wn, g.x, acc.x);
            acc.y = fmaf(wn, g.y, acc.y);
            acc.z = fmaf(wn, g.z, acc.z);
            acc.w = fmaf(wn, g.w, acc.w);
            float u0 = wn * vh.x, u1 = wn * vh.y, u2 = wn * vh.z, u3 = wn * vh.w;
            bool up = (u0 > g.x) | (u1 > g.y) | (u2 > g.z) | (u3 > g.w);
            if (do_upd && up) {
                *gp = make_float4(fmaxf(g.x, u0), fmaxf(g.y, u1), fmaxf(g.z, u2), fmaxf(g.w, u3));
            }
        }
        __shared__ float4 red4[256];
        red4[tid] = acc;
        __syncthreads();
        if (tr == 0) {
            float4 a = red4[c], b4 = red4[128 + c];
            float4 s4 = make_float4(a.x + b4.x, a.y + b4.y, a.z + b4.z, a.w + b4.w);
            float* rp = r_part + (size_t)(t & 1) * (2 * 8 * 16 * 1024);
            reinterpret_cast<float4*>(rp + (size_t)((state * 8 + b) * 16 + rc) * NNN)[m4] = s4;
        }
    }
}

extern "C" void kernel_launch(void* const* d_in, const int* in_sizes, int n_in,
                              void* d_out, int out_size, void* d_ws, size_t ws_size,
                              hipStream_t stream) {
    const float* x   = (const float*)d_in[0];   // [8,48,512]
    const float* tg  = (const float*)d_in[1];   // [8,48,512]
    const float* E   = (const float*)d_in[2];   // [512,1024]
    const float* Dy  = (const float*)d_in[3];   // [1024,512]
    const float* mixp= (const float*)d_in[4];   // scalar
    float* out = (float*)d_out;                 // [8,48,512]

    float* ws = (float*)d_ws;
    float* Gp    = ws;                          // 8*1024*1024
    float* Gt    = Gp + (size_t)8 * 1024 * 1024;
    float* z_x   = Gt + (size_t)8 * 1024 * 1024;    // 384*1024
    float* z_t   = z_x + 384 * 1024;
    float* xn    = z_t + 384 * 1024;
    float* tn    = xn + 384 * 1024;
    float* listw = tn + 384 * 1024;
    int*   listn = (int*)(listw + 384 * 1024);
    int*   cnt   = listn + 384 * 1024;              // 384 ints
    float* r_part = (float*)(cnt + 512);            // 2 bufs * 2*8*16*1024

    k_init<<<4096, 256, 0, stream>>>(Gp, Gt);
    k_gemm_z<<<dim3(48, 4), 256, 0, stream>>>(x, tg, E, z_x, z_t);
    k_ln<<<384, 256, 0, stream>>>(z_x, z_t, xn, tn, listn, listw, cnt);
    for (int t = 0; t < TT; t++) {
        k_step<<<640, 256, 0, stream>>>(Dy, mixp, Gp, Gt, xn, tn, listn, listw, cnt,
                                        r_part, out, t, (t < TT - 1) ? 1 : 0);
    }
    // final y for t = TT-1 (y blocks only)
    k_step<<<128, 256, 0, stream>>>(Dy, mixp, Gp, Gt, xn, tn, listn, listw, cnt,
                                    r_part, out, TT, 0);
}

// Round 2
// 335.396 us; speedup vs baseline: 6.6345x; 6.6345x over previous
//
#include <hip/hip_runtime.h>
#include <math.h>

#define BB 8
#define TT 48
#define DD 512
#define NN 1024

// ---------- z = [x ; tgt_next] @ E : 4x4 register tile per thread ----------
// grid (24,16): 32-row x 64-col tiles. thread: r4=tid>>4 (4 rows), c16=tid&15 (4 cols)
__global__ __launch_bounds__(256) void k_gemm_z(const float* __restrict__ x,
                                                const float* __restrict__ tg,
                                                const float* __restrict__ E,
                                                float* __restrict__ z_x,
                                                float* __restrict__ z_t) {
    int rt = blockIdx.x, ct = blockIdx.y;
    int tid = threadIdx.x;
    int c16 = tid & 15, r4 = tid >> 4;
    int row0 = rt * 32 + r4 * 4;
    int col0 = ct * 64 + c16 * 4;

    const float* rp[4];
#pragma unroll
    for (int i = 0; i < 4; i++) {
        int gr = row0 + i;
        if (gr < BB * TT) {
            rp[i] = x + (size_t)gr * DD;
        } else {
            int bt = gr - BB * TT;
            int s = bt + 1;
            if (s > BB * TT - 1) s = BB * TT - 1;  // t=47 rows: garbage, overwritten by k_ln
            rp[i] = tg + (size_t)s * DD;
        }
    }
    const float* eb = E + col0;

    float acc[4][4];
#pragma unroll
    for (int i = 0; i < 4; i++)
#pragma unroll
        for (int j = 0; j < 4; j++) acc[i][j] = 0.f;

    for (int d0 = 0; d0 < DD; d0 += 4) {
        float a[4][4], e[4][4];
#pragma unroll
        for (int i = 0; i < 4; i++) {
            float4 v = *reinterpret_cast<const float4*>(rp[i] + d0);
            a[i][0] = v.x; a[i][1] = v.y; a[i][2] = v.z; a[i][3] = v.w;
        }
#pragma unroll
        for (int k = 0; k < 4; k++) {
            float4 v = *reinterpret_cast<const float4*>(eb + (size_t)(d0 + k) * NN);
            e[k][0] = v.x; e[k][1] = v.y; e[k][2] = v.z; e[k][3] = v.w;
        }
#pragma unroll
        for (int i = 0; i < 4; i++)
#pragma unroll
            for (int k = 0; k < 4; k++)
#pragma unroll
                for (int j = 0; j < 4; j++)
                    acc[i][j] = fmaf(a[i][k], e[k][j], acc[i][j]);
    }

#pragma unroll
    for (int i = 0; i < 4; i++) {
        int gr = row0 + i;
        float4 v = make_float4(acc[i][0], acc[i][1], acc[i][2], acc[i][3]);
        if (gr < BB * TT)
            *reinterpret_cast<float4*>(z_x + (size_t)gr * NN + col0) = v;
        else
            *reinterpret_cast<float4*>(z_t + (size_t)(gr - BB * TT) * NN + col0) = v;
    }
}

// ---------- LN + relu ----------
__global__ __launch_bounds__(256) void k_ln(const float* __restrict__ z_x,
                                            const float* __restrict__ z_t,
                                            float* __restrict__ xn,
                                            float* __restrict__ tn) {
    int bt = blockIdx.x;
    int t = bt % TT;
    int tid = threadIdx.x;
    __shared__ float rs_[256], rq_[256];

    const float* src = z_x + (size_t)bt * NN;
    float v0 = src[tid], v1 = src[tid + 256], v2 = src[tid + 512], v3 = src[tid + 768];
    rs_[tid] = v0 + v1 + v2 + v3;
    rq_[tid] = v0 * v0 + v1 * v1 + v2 * v2 + v3 * v3;
    __syncthreads();
    for (int off = 128; off > 0; off >>= 1) {
        if (tid < off) { rs_[tid] += rs_[tid + off]; rq_[tid] += rq_[tid + off]; }
        __syncthreads();
    }
    float mu = rs_[0] * (1.f / NN);
    float var = rq_[0] * (1.f / NN) - mu * mu;
    float rstd = rsqrtf(var + 1e-5f);
    float* xrow = xn + (size_t)bt * NN;
    xrow[tid]       = fmaxf((v0 - mu) * rstd, 0.f);
    xrow[tid + 256] = fmaxf((v1 - mu) * rstd, 0.f);
    xrow[tid + 512] = fmaxf((v2 - mu) * rstd, 0.f);
    xrow[tid + 768] = fmaxf((v3 - mu) * rstd, 0.f);
    __syncthreads();  // protect rs_/rq_ reuse

    float* trow = tn + (size_t)bt * NN;
    if (t < TT - 1) {
        const float* s2 = z_t + (size_t)bt * NN;
        float u0 = s2[tid], u1 = s2[tid + 256], u2 = s2[tid + 512], u3 = s2[tid + 768];
        rs_[tid] = u0 + u1 + u2 + u3;
        rq_[tid] = u0 * u0 + u1 * u1 + u2 * u2 + u3 * u3;
        __syncthreads();
        for (int off = 128; off > 0; off >>= 1) {
            if (tid < off) { rs_[tid] += rs_[tid + off]; rq_[tid] += rq_[tid + off]; }
            __syncthreads();
        }
        float mu2 = rs_[0] * (1.f / NN);
        float var2 = rq_[0] * (1.f / NN) - mu2 * mu2;
        float r2 = rsqrtf(var2 + 1e-5f);
        trow[tid]       = fmaxf((u0 - mu2) * r2, 0.f);
        trow[tid + 256] = fmaxf((u1 - mu2) * r2, 0.f);
        trow[tid + 512] = fmaxf((u2 - mu2) * r2, 0.f);
        trow[tid + 768] = fmaxf((u3 - mu2) * r2, 0.f);
    } else {
        trow[tid] = 0.f; trow[tid + 256] = 0.f; trow[tid + 512] = 0.f; trow[tid + 768] = 0.f;
    }
}

// ---------- the whole recurrence, G resident in registers ----------
// 256 blocks: bid = state<<7 | b<<4 | nc. Each thread: G[64 rows][4 cols] in VGPRs.
__global__ __launch_bounds__(256, 1) void k_sweep(const float* __restrict__ xn,
                                                  const float* __restrict__ tn,
                                                  float* __restrict__ r_part) {
    int bid = blockIdx.x;
    int nc = bid & 15, b = (bid >> 4) & 7, state = bid >> 7;
    int tid = threadIdx.x;
    int n0 = nc * 64;
    int m0 = tid * 4;

    float4 g[64];
#pragma unroll
    for (int n = 0; n < 64; n++) {
        float4 v = make_float4(0.f, 0.f, 0.f, 0.f);
        if (state == 0) {
            int nn = n0 + n;
            if (nn == m0)          v.x = 0.5f;
            else if (nn == m0 + 1) v.y = 0.5f;
            else if (nn == m0 + 2) v.z = 0.5f;
            else if (nn == m0 + 3) v.w = 0.5f;
        }
        g[n] = v;
    }

    const float* mvbase = (state ? tn : xn);
    float* rp_out = r_part + (size_t)bid * TT * NN + m0;

#pragma unroll 1
    for (int t = 0; t < TT; t++) {
        const float* xrow = xn + (size_t)(b * TT + t) * NN + n0;
        float4 mv = *reinterpret_cast<const float4*>(mvbase + (size_t)(b * TT + t) * NN + m0);
        float sc = (t < TT - 1) ? 0.5f : 0.0f;   // folds do_upd into the operand
        float mhx = mv.x * sc, mhy = mv.y * sc, mhz = mv.z * sc, mhw = mv.w * sc;
        float ax = 0.f, ay = 0.f, az = 0.f, aw = 0.f;
#pragma unroll
        for (int n = 0; n < 64; n++) {
            float wn = xrow[n];                  // block-uniform -> scalar branch
            if (wn > 0.0f) {
                float4 gv = g[n];
                ax = fmaf(wn, gv.x, ax);
                ay = fmaf(wn, gv.y, ay);
                az = fmaf(wn, gv.z, az);
                aw = fmaf(wn, gv.w, aw);
                g[n].x = fmaxf(gv.x, wn * mhx);
                g[n].y = fmaxf(gv.y, wn * mhy);
                g[n].z = fmaxf(gv.z, wn * mhz);
                g[n].w = fmaxf(gv.w, wn * mhw);
            }
        }
        *reinterpret_cast<float4*>(rp_out + (size_t)t * NN) =
            make_float4(ax, ay, az, aw);
    }
}

// ---------- reduce partials over nc, mix, @Dy, relu ----------
// 128 blocks: b*16 + tg, each handles 3 timesteps
__global__ __launch_bounds__(256) void k_y(const float* __restrict__ r_part,
                                           const float* __restrict__ Dy,
                                           const float* __restrict__ mixp,
                                           float* __restrict__ out) {
    int bb = blockIdx.x;
    int tg = bb & 15, b = bb >> 4;
    int tid = threadIdx.x;
    __shared__ float mixs[3][NN];
    float alpha = 1.f / (1.f + expf(-mixp[0]));

#pragma unroll
    for (int tt = 0; tt < 3; tt++) {
        int t = tg * 3 + tt;
        float spx = 0.f, spy = 0.f, spz = 0.f, spw = 0.f;
        float stx = 0.f, sty = 0.f, stz = 0.f, stw = 0.f;
#pragma unroll
        for (int nc = 0; nc < 16; nc++) {
            int bidp = (0 << 7) | (b << 4) | nc;
            int bidt = (1 << 7) | (b << 4) | nc;
            float4 p = *reinterpret_cast<const float4*>(r_part + ((size_t)bidp * TT + t) * NN + tid * 4);
            float4 q = *reinterpret_cast<const float4*>(r_part + ((size_t)bidt * TT + t) * NN + tid * 4);
            spx += p.x; spy += p.y; spz += p.z; spw += p.w;
            stx += q.x; sty += q.y; stz += q.z; stw += q.w;
        }
        float4 m4;
        m4.x = alpha * spx + (1.f - alpha) * stx;
        m4.y = alpha * spy + (1.f - alpha) * sty;
        m4.z = alpha * spz + (1.f - alpha) * stz;
        m4.w = alpha * spw + (1.f - alpha) * stw;
        *reinterpret_cast<float4*>(&mixs[tt][tid * 4]) = m4;
    }
    __syncthreads();

    float acc[3][2];
#pragma unroll
    for (int tt = 0; tt < 3; tt++) { acc[tt][0] = 0.f; acc[tt][1] = 0.f; }

    for (int m = 0; m < NN; m += 4) {
        float w[3][4];
#pragma unroll
        for (int tt = 0; tt < 3; tt++) {
            float4 v = *reinterpret_cast<const float4*>(&mixs[tt][m]);
            w[tt][0] = v.x; w[tt][1] = v.y; w[tt][2] = v.z; w[tt][3] = v.w;
        }
#pragma unroll
        for (int j = 0; j < 4; j++) {
            float d0 = Dy[(size_t)(m + j) * DD + tid];
            float d1 = Dy[(size_t)(m + j) * DD + tid + 256];
#pragma unroll
            for (int tt = 0; tt < 3; tt++) {
                acc[tt][0] = fmaf(w[tt][j], d0, acc[tt][0]);
                acc[tt][1] = fmaf(w[tt][j], d1, acc[tt][1]);
            }
        }
    }
#pragma unroll
    for (int tt = 0; tt < 3; tt++) {
        int t = tg * 3 + tt;
        out[((size_t)b * TT + t) * DD + tid]       = fmaxf(acc[tt][0], 0.f);
        out[((size_t)b * TT + t) * DD + tid + 256] = fmaxf(acc[tt][1], 0.f);
    }
}

extern "C" void kernel_launch(void* const* d_in, const int* in_sizes, int n_in,
                              void* d_out, int out_size, void* d_ws, size_t ws_size,
                              hipStream_t stream) {
    const float* x    = (const float*)d_in[0];   // [8,48,512]
    const float* tg   = (const float*)d_in[1];   // [8,48,512]
    const float* E    = (const float*)d_in[2];   // [512,1024]
    const float* Dy   = (const float*)d_in[3];   // [1024,512]
    const float* mixp = (const float*)d_in[4];   // scalar
    float* out = (float*)d_out;                  // [8,48,512]

    float* ws = (float*)d_ws;
    float* z_x    = ws;                               // 384*1024
    float* z_t    = z_x + (size_t)384 * 1024;
    float* xn     = z_t + (size_t)384 * 1024;
    float* tn     = xn + (size_t)384 * 1024;
    float* r_part = tn + (size_t)384 * 1024;          // 256 * 48 * 1024

    k_gemm_z<<<dim3(24, 16), 256, 0, stream>>>(x, tg, E, z_x, z_t);
    k_ln<<<384, 256, 0, stream>>>(z_x, z_t, xn, tn);
    k_sweep<<<256, 256, 0, stream>>>(xn, tn, r_part);
    k_y<<<128, 256, 0, stream>>>(r_part, Dy, mixp, out);
}

// Round 3
// 249.569 us; speedup vs baseline: 8.9161x; 1.3439x over previous
//
#include <hip/hip_runtime.h>
#include <math.h>

#define BB 8
#define TT 48
#define DD 512
#define NN 1024

// ---------- z = [x ; tgt_next] @ E : 4x4 register tile per thread ----------
__global__ __launch_bounds__(256) void k_gemm_z(const float* __restrict__ x,
                                                const float* __restrict__ tg,
                                                const float* __restrict__ E,
                                                float* __restrict__ z_x,
                                                float* __restrict__ z_t) {
    int rt = blockIdx.x, ct = blockIdx.y;
    int tid = threadIdx.x;
    int c16 = tid & 15, r4 = tid >> 4;
    int row0 = rt * 32 + r4 * 4;
    int col0 = ct * 64 + c16 * 4;

    const float* rp[4];
#pragma unroll
    for (int i = 0; i < 4; i++) {
        int gr = row0 + i;
        if (gr < BB * TT) {
            rp[i] = x + (size_t)gr * DD;
        } else {
            int bt = gr - BB * TT;
            int s = bt + 1;
            if (s > BB * TT - 1) s = BB * TT - 1;  // t=47 rows: garbage, masked by k_ln
            rp[i] = tg + (size_t)s * DD;
        }
    }
    const float* eb = E + col0;

    float acc[4][4];
#pragma unroll
    for (int i = 0; i < 4; i++)
#pragma unroll
        for (int j = 0; j < 4; j++) acc[i][j] = 0.f;

    for (int d0 = 0; d0 < DD; d0 += 4) {
        float a[4][4], e[4][4];
#pragma unroll
        for (int i = 0; i < 4; i++) {
            float4 v = *reinterpret_cast<const float4*>(rp[i] + d0);
            a[i][0] = v.x; a[i][1] = v.y; a[i][2] = v.z; a[i][3] = v.w;
        }
#pragma unroll
        for (int k = 0; k < 4; k++) {
            float4 v = *reinterpret_cast<const float4*>(eb + (size_t)(d0 + k) * NN);
            e[k][0] = v.x; e[k][1] = v.y; e[k][2] = v.z; e[k][3] = v.w;
        }
#pragma unroll
        for (int i = 0; i < 4; i++)
#pragma unroll
            for (int k = 0; k < 4; k++)
#pragma unroll
                for (int j = 0; j < 4; j++)
                    acc[i][j] = fmaf(a[i][k], e[k][j], acc[i][j]);
    }

#pragma unroll
    for (int i = 0; i < 4; i++) {
        int gr = row0 + i;
        float4 v = make_float4(acc[i][0], acc[i][1], acc[i][2], acc[i][3]);
        if (gr < BB * TT)
            *reinterpret_cast<float4*>(z_x + (size_t)gr * NN + col0) = v;
        else
            *reinterpret_cast<float4*>(z_t + (size_t)(gr - BB * TT) * NN + col0) = v;
    }
}

// ---------- LN + relu ----------
__global__ __launch_bounds__(256) void k_ln(const float* __restrict__ z_x,
                                            const float* __restrict__ z_t,
                                            float* __restrict__ xn,
                                            float* __restrict__ tn) {
    int bt = blockIdx.x;
    int t = bt % TT;
    int tid = threadIdx.x;
    __shared__ float rs_[256], rq_[256];

    const float* src = z_x + (size_t)bt * NN;
    float v0 = src[tid], v1 = src[tid + 256], v2 = src[tid + 512], v3 = src[tid + 768];
    rs_[tid] = v0 + v1 + v2 + v3;
    rq_[tid] = v0 * v0 + v1 * v1 + v2 * v2 + v3 * v3;
    __syncthreads();
    for (int off = 128; off > 0; off >>= 1) {
        if (tid < off) { rs_[tid] += rs_[tid + off]; rq_[tid] += rq_[tid + off]; }
        __syncthreads();
    }
    float mu = rs_[0] * (1.f / NN);
    float var = rq_[0] * (1.f / NN) - mu * mu;
    float rstd = rsqrtf(var + 1e-5f);
    float* xrow = xn + (size_t)bt * NN;
    xrow[tid]       = fmaxf((v0 - mu) * rstd, 0.f);
    xrow[tid + 256] = fmaxf((v1 - mu) * rstd, 0.f);
    xrow[tid + 512] = fmaxf((v2 - mu) * rstd, 0.f);
    xrow[tid + 768] = fmaxf((v3 - mu) * rstd, 0.f);
    __syncthreads();

    float* trow = tn + (size_t)bt * NN;
    if (t < TT - 1) {
        const float* s2 = z_t + (size_t)bt * NN;
        float u0 = s2[tid], u1 = s2[tid + 256], u2 = s2[tid + 512], u3 = s2[tid + 768];
        rs_[tid] = u0 + u1 + u2 + u3;
        rq_[tid] = u0 * u0 + u1 * u1 + u2 * u2 + u3 * u3;
        __syncthreads();
        for (int off = 128; off > 0; off >>= 1) {
            if (tid < off) { rs_[tid] += rs_[tid + off]; rq_[tid] += rq_[tid + off]; }
            __syncthreads();
        }
        float mu2 = rs_[0] * (1.f / NN);
        float var2 = rq_[0] * (1.f / NN) - mu2 * mu2;
        float r2 = rsqrtf(var2 + 1e-5f);
        trow[tid]       = fmaxf((u0 - mu2) * r2, 0.f);
        trow[tid + 256] = fmaxf((u1 - mu2) * r2, 0.f);
        trow[tid + 512] = fmaxf((u2 - mu2) * r2, 0.f);
        trow[tid + 768] = fmaxf((u3 - mu2) * r2, 0.f);
    } else {
        trow[tid] = 0.f; trow[tid + 256] = 0.f; trow[tid + 512] = 0.f; trow[tid + 768] = 0.f;
    }
}

// ---------- the whole recurrence, G resident in registers ----------
// 512 blocks: bid = state<<8 | b<<5 | nc<<1 | mc.
// Each thread: G[64 rows][2 cols] = 128 VGPRs. Row weights via readlane (scalar branch).
__global__ __launch_bounds__(256, 2) void k_sweep(const float* __restrict__ xn,
                                                  const float* __restrict__ tn,
                                                  float* __restrict__ r_part) {
    int bid = blockIdx.x;
    int mc = bid & 1, nc = (bid >> 1) & 15, b = (bid >> 5) & 7, state = bid >> 8;
    int tid = threadIdx.x;
    int lane = tid & 63;
    int n0 = nc * 64;
    int m0 = mc * 512 + tid * 2;

    float2 g[64];
#pragma unroll
    for (int n = 0; n < 64; n++) {
        float2 v = make_float2(0.f, 0.f);
        if (state == 0) {
            int nn = n0 + n;
            if (nn == m0)          v.x = 0.5f;
            else if (nn == m0 + 1) v.y = 0.5f;
        }
        g[n] = v;
    }

    const float* mvbase = (state ? tn : xn);
    float* rp_out = r_part + ((size_t)((state * 8 + b) * 16 + nc) * TT) * NN + m0;

#pragma unroll 1
    for (int t = 0; t < TT; t++) {
        const float* xrow = xn + (size_t)(b * TT + t) * NN + n0;
        float wv = xrow[lane];                 // 64 row-weights live in the wave's lanes
        float2 mv = *reinterpret_cast<const float2*>(mvbase + (size_t)(b * TT + t) * NN + m0);
        float sc = (t < TT - 1) ? 0.5f : 0.0f; // folds do_upd into the operand
        float mhx = mv.x * sc, mhy = mv.y * sc;
        float ax[4] = {0.f, 0.f, 0.f, 0.f};
        float ay[4] = {0.f, 0.f, 0.f, 0.f};
#pragma unroll
        for (int n = 0; n < 64; n++) {
            float wn = __int_as_float(__builtin_amdgcn_readlane(__float_as_int(wv), n));
            if (wn > 0.0f) {                   // uniform (SGPR) -> scalar branch
                float2 gv = g[n];
                ax[n & 3] = fmaf(wn, gv.x, ax[n & 3]);
                ay[n & 3] = fmaf(wn, gv.y, ay[n & 3]);
                g[n].x = fmaxf(gv.x, wn * mhx);
                g[n].y = fmaxf(gv.y, wn * mhy);
            }
        }
        float axs = (ax[0] + ax[1]) + (ax[2] + ax[3]);
        float ays = (ay[0] + ay[1]) + (ay[2] + ay[3]);
        *reinterpret_cast<float2*>(rp_out + (size_t)t * NN) = make_float2(axs, ays);
    }
}

// ---------- reduce partials over nc, mix, @Dy, relu ----------
__global__ __launch_bounds__(256) void k_y(const float* __restrict__ r_part,
                                           const float* __restrict__ Dy,
                                           const float* __restrict__ mixp,
                                           float* __restrict__ out) {
    int bb = blockIdx.x;
    int tg = bb & 15, b = bb >> 4;
    int tid = threadIdx.x;
    __shared__ float mixs[3][NN];
    float alpha = 1.f / (1.f + expf(-mixp[0]));

#pragma unroll
    for (int tt = 0; tt < 3; tt++) {
        int t = tg * 3 + tt;
        float spx = 0.f, spy = 0.f, spz = 0.f, spw = 0.f;
        float stx = 0.f, sty = 0.f, stz = 0.f, stw = 0.f;
#pragma unroll
        for (int nc = 0; nc < 16; nc++) {
            int bidp = (b * 16 + nc);
            int bidt = ((8 + b) * 16 + nc);
            float4 p = *reinterpret_cast<const float4*>(r_part + ((size_t)bidp * TT + t) * NN + tid * 4);
            float4 q = *reinterpret_cast<const float4*>(r_part + ((size_t)bidt * TT + t) * NN + tid * 4);
            spx += p.x; spy += p.y; spz += p.z; spw += p.w;
            stx += q.x; sty += q.y; stz += q.z; stw += q.w;
        }
        float4 m4;
        m4.x = alpha * spx + (1.f - alpha) * stx;
        m4.y = alpha * spy + (1.f - alpha) * sty;
        m4.z = alpha * spz + (1.f - alpha) * stz;
        m4.w = alpha * spw + (1.f - alpha) * stw;
        *reinterpret_cast<float4*>(&mixs[tt][tid * 4]) = m4;
    }
    __syncthreads();

    float acc[3][2];
#pragma unroll
    for (int tt = 0; tt < 3; tt++) { acc[tt][0] = 0.f; acc[tt][1] = 0.f; }

    for (int m = 0; m < NN; m += 4) {
        float w[3][4];
#pragma unroll
        for (int tt = 0; tt < 3; tt++) {
            float4 v = *reinterpret_cast<const float4*>(&mixs[tt][m]);
            w[tt][0] = v.x; w[tt][1] = v.y; w[tt][2] = v.z; w[tt][3] = v.w;
        }
#pragma unroll
        for (int j = 0; j < 4; j++) {
            float d0 = Dy[(size_t)(m + j) * DD + tid];
            float d1 = Dy[(size_t)(m + j) * DD + tid + 256];
#pragma unroll
            for (int tt = 0; tt < 3; tt++) {
                acc[tt][0] = fmaf(w[tt][j], d0, acc[tt][0]);
                acc[tt][1] = fmaf(w[tt][j], d1, acc[tt][1]);
            }
        }
    }
#pragma unroll
    for (int tt = 0; tt < 3; tt++) {
        int t = tg * 3 + tt;
        out[((size_t)b * TT + t) * DD + tid]       = fmaxf(acc[tt][0], 0.f);
        out[((size_t)b * TT + t) * DD + tid + 256] = fmaxf(acc[tt][1], 0.f);
    }
}

extern "C" void kernel_launch(void* const* d_in, const int* in_sizes, int n_in,
                              void* d_out, int out_size, void* d_ws, size_t ws_size,
                              hipStream_t stream) {
    const float* x    = (const float*)d_in[0];   // [8,48,512]
    const float* tg   = (const float*)d_in[1];   // [8,48,512]
    const float* E    = (const float*)d_in[2];   // [512,1024]
    const float* Dy   = (const float*)d_in[3];   // [1024,512]
    const float* mixp = (const float*)d_in[4];   // scalar
    float* out = (float*)d_out;                  // [8,48,512]

    float* ws = (float*)d_ws;
    float* z_x    = ws;                               // 384*1024
    float* z_t    = z_x + (size_t)384 * 1024;
    float* xn     = z_t + (size_t)384 * 1024;
    float* tn     = xn + (size_t)384 * 1024;
    float* r_part = tn + (size_t)384 * 1024;          // 256 * 48 * 1024 floats

    k_gemm_z<<<dim3(24, 16), 256, 0, stream>>>(x, tg, E, z_x, z_t);
    k_ln<<<384, 256, 0, stream>>>(z_x, z_t, xn, tn);
    k_sweep<<<512, 256, 0, stream>>>(xn, tn, r_part);
    k_y<<<128, 256, 0, stream>>>(r_part, Dy, mixp, out);
}